// Round 3
// baseline (335.853 us; speedup 1.0000x reference)
//
#include <hip/hip_runtime.h>
#include <hip/hip_cooperative_groups.h>
#include <math.h>

#define HID   2048
#define NEXP  64
#define NTOK  16384
#define SBLK  64      // sinkhorn blocks
#define TOLF  1e-4f
#define EPSF  1e-8f

typedef _Float16 f16x8 __attribute__((ext_vector_type(8)));
typedef float    f32x4 __attribute__((ext_vector_type(4)));

// ---------------------------------------------------------------------------
// Kernel 0: split W (64x2048 fp32) into Wh + Wl*2048 (f16, same [e][k] layout).
// f16x3 trick: x@W ~= xh@Wh + (xh@Wl' + xl'@Wh)/2048, residuals exact
// (Sterbenz), net error ~2^-24 * scale -- below fp32 reassociation noise.
// ---------------------------------------------------------------------------
__global__ __launch_bounds__(256) void convert_w(const float* __restrict__ W,
                                                 _Float16* __restrict__ Wh,
                                                 _Float16* __restrict__ Wl) {
    const int i = ((int)blockIdx.x * 256 + (int)threadIdx.x) * 8;
    const float4 w0 = *(const float4*)(W + i);
    const float4 w1 = *(const float4*)(W + i + 4);
    float v[8] = {w0.x, w0.y, w0.z, w0.w, w1.x, w1.y, w1.z, w1.w};
    f16x8 h, l;
#pragma unroll
    for (int j = 0; j < 8; ++j) {
        const _Float16 hh = (_Float16)v[j];
        h[j] = hh;
        l[j] = (_Float16)((v[j] - (float)hh) * 2048.0f);
    }
    *(f16x8*)(Wh + i) = h;
    *(f16x8*)(Wl + i) = l;
}

// ---------------------------------------------------------------------------
// Kernel 1: logits via f16x3 MFMA, split-K across waves for occupancy.
// R2 post-mortem: 256-block grid = 1 wave/SIMD -> latency-bound 100us
// (Occupancy 10%, VALUBusy 6.7%, hbm 9%). Fix = TLP: grid 1024 blocks x
// 4 waves; block = 16 tokens; wave w = k-slice [w*512,(w+1)*512).
// 4096 waves -> 4 blocks/CU = 16 waves/CU = 4/SIMD (VGPR<=128 ceiling,
// pinned by __launch_bounds__(256,4)). Split-K partials reduced in-block
// via 16KB LDS -- no extra dispatch, no global partial traffic.
// A-fragment (16x16x32 f16): lane(l&15)=token row, 8 k-elems at k-block
// (l>>4)*8 -- wave's fp32 global loads = 16 rows x 128B contiguous.
// B reads Wh/Wl f16 rows directly (512KB, L2/L3-resident).
// C/D layout (verified, dtype-independent): col=lane&15, row=(lane>>4)*4+r.
// ---------------------------------------------------------------------------
__global__ __launch_bounds__(256, 4) void gemm_mfma(const float* __restrict__ x,
                                                    const _Float16* __restrict__ Wh,
                                                    const _Float16* __restrict__ Wl,
                                                    float* __restrict__ L) {
    __shared__ float red[4][1024];   // [wave][n*256 + r*64 + lane], 16 KB

    const int wave = (int)threadIdx.x >> 6;
    const int lane = (int)threadIdx.x & 63;
    const int lo = lane & 15;        // token row (A) / expert col (B,D)
    const int hi = lane >> 4;        // k-block 0..3 (A,B) / row-group (D)
    const int t0 = (int)blockIdx.x * 16;
    const int kb = wave * 512;       // this wave's k-slice

    const float*    xp  = x  + (size_t)(t0 + lo) * HID + kb + hi * 8;
    const _Float16* bhp = Wh + (size_t)lo * HID + kb + hi * 8;
    const _Float16* blp = Wl + (size_t)lo * HID + kb + hi * 8;

    f32x4 acc_hh[4], acc_hl[4];
#pragma unroll
    for (int n = 0; n < 4; ++n) {
        acc_hh[n] = f32x4{0.f, 0.f, 0.f, 0.f};
        acc_hl[n] = f32x4{0.f, 0.f, 0.f, 0.f};
    }

    // 1-step-ahead A prefetch (A is the HBM-latency chain; B is L2-resident).
    float4 a0n = *(const float4*)(xp);
    float4 a1n = *(const float4*)(xp + 4);

#pragma unroll 2
    for (int s = 0; s < 16; ++s) {
        const float4 a0 = a0n, a1 = a1n;

        // issue next step's A loads early (clamped re-read at the tail)
        const int ko = ((s + 1 < 16) ? (s + 1) : 15) * 32;
        a0n = *(const float4*)(xp + ko);
        a1n = *(const float4*)(xp + ko + 4);

        // B for this step (L2-resident, 4 waves/SIMD cover ~200cyc latency)
        f16x8 bh[4], bl[4];
#pragma unroll
        for (int n = 0; n < 4; ++n) {
            bh[n] = *(const f16x8*)(bhp + n * 16 * HID + s * 32);
            bl[n] = *(const f16x8*)(blp + n * 16 * HID + s * 32);
        }

        // split current A chunk: xh (RTN) + xl*2048 (residual exact)
        f16x8 ah, al;
        const float av[8] = {a0.x, a0.y, a0.z, a0.w, a1.x, a1.y, a1.z, a1.w};
#pragma unroll
        for (int j = 0; j < 8; ++j) {
            const _Float16 hh = (_Float16)av[j];
            ah[j] = hh;
            al[j] = (_Float16)((av[j] - (float)hh) * 2048.0f);
        }

        // 12 MFMA; dependent acc_hl pairs separated by 4 independent MFMAs
#pragma unroll
        for (int n = 0; n < 4; ++n)
            acc_hh[n] = __builtin_amdgcn_mfma_f32_16x16x32_f16(ah, bh[n], acc_hh[n], 0, 0, 0);
#pragma unroll
        for (int n = 0; n < 4; ++n)
            acc_hl[n] = __builtin_amdgcn_mfma_f32_16x16x32_f16(ah, bl[n], acc_hl[n], 0, 0, 0);
#pragma unroll
        for (int n = 0; n < 4; ++n)
            acc_hl[n] = __builtin_amdgcn_mfma_f32_16x16x32_f16(al, bh[n], acc_hl[n], 0, 0, 0);
    }

    // per-wave partials -> LDS
#pragma unroll
    for (int n = 0; n < 4; ++n)
#pragma unroll
        for (int r = 0; r < 4; ++r)
            red[wave][n * 256 + r * 64 + lane] =
                acc_hh[n][r] + acc_hl[n][r] * (1.0f / 2048.0f);
    __syncthreads();

    // cross-wave reduce + coalesced write. Thread tid owns outputs
    // o = tid*4 .. +3: t_loc = o>>6, e = o&63. Source LDS index for (t_loc,e):
    // lane_src = (t_loc>>2)*16 + (e&15); idx = (e>>4)*256 + (t_loc&3)*64 + lane_src
    // -- consecutive for the 4 outputs, so float4 reads (conflict-free).
    {
        const int o     = (int)threadIdx.x * 4;
        const int t_loc = o >> 6;
        const int e     = o & 63;
        const int idx   = (e >> 4) * 256 + (t_loc & 3) * 64 + (t_loc >> 2) * 16 + (e & 15);
        float4 s = *(const float4*)&red[0][idx];
#pragma unroll
        for (int q = 1; q < 4; ++q) {
            const float4 v = *(const float4*)&red[q][idx];
            s.x += v.x; s.y += v.y; s.z += v.z; s.w += v.w;
        }
        *(float4*)(L + (size_t)(t0 + t_loc) * NEXP + e) = s;
    }
}

// ---------------------------------------------------------------------------
// Kernel 2 (cooperative): sinkhorn + top-2 + softmax gather. UNCHANGED from
// the 302us baseline. Grid = 64 blocks x 1024 threads. Wave w (0..15) of
// block b owns tokens b*256 + w*16 .. +15; lane = expert. cost in registers.
// ---------------------------------------------------------------------------
__global__ __launch_bounds__(1024) void sinkhorn_router(const float* __restrict__ L,
                                                        float* __restrict__ colbuf,
                                                        float* __restrict__ out,
                                                        int nh) {
    cooperative_groups::grid_group grid = cooperative_groups::this_grid();

    __shared__ float part[16][64];
    __shared__ float redq[64][17];
    __shared__ float d1s[64];
    __shared__ float err_s;

    const int b     = blockIdx.x;   // 0..63
    const int tid   = (int)threadIdx.x;
    const int w     = tid >> 6;     // wave 0..15
    const int lane  = tid & 63;     // expert index
    const int tbase = b * 256 + w * 16;

    float logit[16], cost[16], dreg[16];
#pragma unroll
    for (int j = 0; j < 16; ++j) {
        const int t = tbase + j;
        float l = L[(size_t)t * NEXP + lane];
        for (int h = 1; h < nh; ++h)
            l += L[(size_t)h * NTOK * NEXP + (size_t)t * NEXP + lane];
        logit[j] = l;
        cost[j]  = expf(l);
        dreg[j]  = 0.0f;
    }

    float d1l   = 1.0f;   // this lane's d1[e]
    float d1old = 1.0f;   // previous d1 (used by tid<64 for err)
    int   g     = 0;

    for (;;) {
        // ---- phase A: d0 per token + per-wave column partials ----
        float colacc = 0.0f;
#pragma unroll
        for (int j = 0; j < 16; ++j) {
            float s = d1l * cost[j];
#pragma unroll
            for (int m = 32; m; m >>= 1) s += __shfl_xor(s, m, 64);
            const float d0 = (1.0f / 16384.0f) / (s + EPSF);
            dreg[j] = d0;
            colacc = fmaf(d0, cost[j], colacc);
        }
        part[w][lane] = colacc;
        __syncthreads();

        float* cb = colbuf + (size_t)(g & 1) * (NEXP * SBLK);
        if (tid < 64) {
            float s = part[0][tid];
#pragma unroll
            for (int q = 1; q < 16; ++q) s += part[q][tid];
            cb[tid * SBLK + b] = s;     // reader-coalesced layout [e][b]
        }
        grid.sync();

        // ---- phase B: cross-block column reduction, all 1024 threads ----
        {
            const int e = tid >> 4;     // 0..63
            const int q = tid & 15;     // 0..15 -> blocks q*4..q*4+3
            const float4 v = *(const float4*)(cb + e * SBLK + q * 4);
            redq[e][q] = (v.x + v.y) + (v.z + v.w);
        }
        __syncthreads();

        if (tid < 64) {
            float tot = redq[tid][0];
#pragma unroll
            for (int q = 1; q < 16; ++q) tot += redq[tid][q];
            const float d1n = (1.0f / 64.0f) / (tot + EPSF);
            float diff = fabsf(d1old - d1n);
#pragma unroll
            for (int m = 32; m; m >>= 1) diff += __shfl_xor(diff, m, 64);
            d1s[tid] = d1n;
            d1old    = d1n;
            if (tid == 0) err_s = diff * (1.0f / 64.0f);
        }
        __syncthreads();
        d1l = d1s[lane];
        const float err = err_s;
        ++g;
        if (!(err > TOLF) || g >= 512) break;   // matches while(err>tol); NaN stops
    }

    // ---- final: per token top-2 of d1*cost*d0, softmax gather ----
#pragma unroll 1
    for (int j = 0; j < 16; ++j) {
        const int t = tbase + j;
        const float v = (d1l * cost[j]) * dreg[j];

        float bv = v; int bi = lane;
#pragma unroll
        for (int m = 32; m; m >>= 1) {
            const float ov = __shfl_xor(bv, m, 64);
            const int   oi = __shfl_xor(bi, m, 64);
            if (ov > bv || (ov == bv && oi < bi)) { bv = ov; bi = oi; }
        }
        const int i1 = bi;

        const float v2 = (lane == i1) ? -INFINITY : v;
        float bv2 = v2; int bi2 = lane;
#pragma unroll
        for (int m = 32; m; m >>= 1) {
            const float ov = __shfl_xor(bv2, m, 64);
            const int   oi = __shfl_xor(bi2, m, 64);
            if (ov > bv2 || (ov == bv2 && oi < bi2)) { bv2 = ov; bi2 = oi; }
        }
        const int i2 = bi2;

        float mx = logit[j];
#pragma unroll
        for (int m = 32; m; m >>= 1) mx = fmaxf(mx, __shfl_xor(mx, m, 64));
        const float e = expf(logit[j] - mx);
        float se = e;
#pragma unroll
        for (int m = 32; m; m >>= 1) se += __shfl_xor(se, m, 64);

        const float p1 = __shfl(e, i1, 64) / se;
        const float p2 = __shfl(e, i2, 64) / se;

        if (lane == 0) {
            out[(size_t)t * 2 + 0] = p1;
            out[(size_t)t * 2 + 1] = p2;
            out[(size_t)NTOK * 2 + (size_t)t * 2 + 0] = (float)i1;
            out[(size_t)NTOK * 2 + (size_t)t * 2 + 1] = (float)i2;
        }
    }
}

// ---------------------------------------------------------------------------
// ws layout (4.78 MB total, well under the proven-available 8.4 MB minimum):
//   [0,       256KB)  Wh f16 [64][2048]
//   [256KB,   512KB)  Wl f16 [64][2048] (pre-scaled x2048)
//   [512KB,   4.5MB)  L  f32 [16384][64]
//   [4.5MB,  +32KB )  colbuf (2 x 64 x 64 f32, sinkhorn ping-pong)
// ---------------------------------------------------------------------------
extern "C" void kernel_launch(void* const* d_in, const int* in_sizes, int n_in,
                              void* d_out, int out_size, void* d_ws, size_t ws_size,
                              hipStream_t stream) {
    const float* x = (const float*)d_in[0];
    const float* W = (const float*)d_in[1];
    float* out = (float*)d_out;

    _Float16* Wh = (_Float16*)d_ws;
    _Float16* Wl = Wh + (size_t)NEXP * HID;                  // +131072 elems
    float* L      = (float*)((char*)d_ws + 524288);
    float* colbuf = L + (size_t)NTOK * NEXP;

    convert_w<<<dim3(64), dim3(256), 0, stream>>>(W, Wh, Wl);
    gemm_mfma<<<dim3(1024), dim3(256), 0, stream>>>(x, Wh, Wl, L);

    int nh = 1;
    void* args[] = { (void*)&L, (void*)&colbuf, (void*)&out, (void*)&nh };
    hipLaunchCooperativeKernel((void*)sinkhorn_router, dim3(SBLK), dim3(1024),
                               args, 0, stream);
}

// Round 4
// 299.106 us; speedup vs baseline: 1.1229x; 1.1229x over previous
//
#include <hip/hip_runtime.h>
#include <hip/hip_cooperative_groups.h>
#include <math.h>

#define HID   2048
#define NEXP  64
#define NTOK  16384
#define SBLK  64      // sinkhorn blocks
#define TOLF  1e-4f
#define EPSF  1e-8f

typedef _Float16 f16x8 __attribute__((ext_vector_type(8)));
typedef float    f32x4 __attribute__((ext_vector_type(4)));

// ---------------------------------------------------------------------------
// Kernel 0: split W (64x2048 fp32) into Wh + Wl*2048 (f16, same [e][k] layout).
// f16x3 trick: x@W ~= xh@Wh + (xh@Wl' + xl'@Wh)/2048, residuals exact
// (Sterbenz), net error ~2^-24 * scale -- below fp32 reassociation noise.
// ---------------------------------------------------------------------------
__global__ __launch_bounds__(256) void convert_w(const float* __restrict__ W,
                                                 _Float16* __restrict__ Wh,
                                                 _Float16* __restrict__ Wl) {
    const int i = ((int)blockIdx.x * 256 + (int)threadIdx.x) * 8;
    const float4 w0 = *(const float4*)(W + i);
    const float4 w1 = *(const float4*)(W + i + 4);
    float v[8] = {w0.x, w0.y, w0.z, w0.w, w1.x, w1.y, w1.z, w1.w};
    f16x8 h, l;
#pragma unroll
    for (int j = 0; j < 8; ++j) {
        const _Float16 hh = (_Float16)v[j];
        h[j] = hh;
        l[j] = (_Float16)((v[j] - (float)hh) * 2048.0f);
    }
    *(f16x8*)(Wh + i) = h;
    *(f16x8*)(Wl + i) = l;
}

// ---------------------------------------------------------------------------
// Kernel 1: f16x3 MFMA logits, B staged through LDS.
// R3 post-mortem: dur invariant at ~100us across 3x occupancy change =>
// bottleneck is VMEM per-cache-line issue (~1.7 cyc/line/CU): B-fragment
// loads scattered 16 lines/instr, 131K line-touches/CU (89% of demand).
// Fix: block = 64 tokens x 16 waves (4 token-groups x 4 k-slices), grid =
// 256 = 1 block/CU. Each k-group's 256 thr stage its 8KB B-chunk (K=32)
// coalesced into LDS once per chunk; fragments via ds_read_b128.
// B line-touches/CU: 131K -> 8K; total ~24K -> ~17us expected.
// LDS B stride 40 f16 (80B): read granule pos = (5*row+hi)%8, even spread.
// A-fragments stay direct-global (16K touches, 128B segments).
// Split-K reduced in-block (R3 epilogue); accumulation order identical to
// R3 -> bitwise-same L. red[] aliases B buffer after the last barrier.
// ---------------------------------------------------------------------------
#define BSTRIDE 40   // f16 per LDS B row (32 data + 8 pad, 16B-aligned)

__global__ __launch_bounds__(1024, 4) void gemm_mfma(const float* __restrict__ x,
                                                     const _Float16* __restrict__ Wh,
                                                     const _Float16* __restrict__ Wl,
                                                     float* __restrict__ L) {
    // 64 KB static LDS: B chunks (40960 B) during the loop, red[16][1024]
    // f32 (65536 B) in the epilogue (aliased; safe after final barrier).
    __shared__ __align__(16) char smem[65536];
    _Float16* Bs  = (_Float16*)smem;   // [(wk*2+a)*64 + row][BSTRIDE]
    float*    red = (float*)smem;      // [wave][n*256 + r*64 + lane]

    const int tid    = (int)threadIdx.x;
    const int waveid = tid >> 6;       // 0..15
    const int wt     = waveid >> 2;    // token group 0..3 (16 tokens each)
    const int wk     = waveid & 3;     // k-slice 0..3 (512 k each)
    const int lane   = tid & 63;
    const int lo     = lane & 15;      // token row (A) / expert col (D)
    const int hi     = lane >> 4;      // k-block 0..3
    const int t0     = (int)blockIdx.x * 64;
    const int kb     = wk * 512;

    // staging assignment: group-local thread gt (0..255) loads 32B of B
    const int gt    = wt * 64 + lane;  // group-local tid
    const int sa    = gt >> 7;         // 0 = Wh, 1 = Wl
    const int srow  = (gt & 127) >> 1; // 0..63
    const int shalf = (gt & 1) * 16;   // 0 or 16 (f16)
    const _Float16* sgp = (sa ? Wl : Wh) + (size_t)srow * HID + kb + shalf;
    const int swbase = ((wk * 2 + sa) * 64 + srow) * BSTRIDE + shalf;

    const float* xp = x + (size_t)(t0 + wt * 16 + lo) * HID + kb + hi * 8;

    f32x4 acc_hh[4], acc_hl[4];
#pragma unroll
    for (int n = 0; n < 4; ++n) {
        acc_hh[n] = f32x4{0.f, 0.f, 0.f, 0.f};
        acc_hl[n] = f32x4{0.f, 0.f, 0.f, 0.f};
    }

    // prologue: stage chunk 0
    f16x8 sr0 = *(const f16x8*)(sgp);
    f16x8 sr1 = *(const f16x8*)(sgp + 8);
    *(f16x8*)&Bs[swbase]     = sr0;
    *(f16x8*)&Bs[swbase + 8] = sr1;
    __syncthreads();

    // 1-step-ahead A prefetch (A is the only remaining direct-global path)
    float4 a0n = *(const float4*)(xp);
    float4 a1n = *(const float4*)(xp + 4);

    for (int c = 0; c < 16; ++c) {
        // issue next chunk's B staging loads early (no wait here)
        if (c + 1 < 16) {
            sr0 = *(const f16x8*)(sgp + (c + 1) * 32);
            sr1 = *(const f16x8*)(sgp + (c + 1) * 32 + 8);
        }

        const float4 a0 = a0n, a1 = a1n;
        // next step's A loads (clamped re-read at the tail)
        const int ko = ((c + 1 < 16) ? (c + 1) : 15) * 32;
        a0n = *(const float4*)(xp + ko);
        a1n = *(const float4*)(xp + ko + 4);

        // B fragments from LDS
        f16x8 bh[4], bl[4];
#pragma unroll
        for (int n = 0; n < 4; ++n) {
            bh[n] = *(const f16x8*)&Bs[((wk * 2 + 0) * 64 + lo + n * 16) * BSTRIDE + hi * 8];
            bl[n] = *(const f16x8*)&Bs[((wk * 2 + 1) * 64 + lo + n * 16) * BSTRIDE + hi * 8];
        }

        // split current A chunk: xh (RTN) + xl*2048 (residual exact)
        f16x8 ah, al;
        const float av[8] = {a0.x, a0.y, a0.z, a0.w, a1.x, a1.y, a1.z, a1.w};
#pragma unroll
        for (int j = 0; j < 8; ++j) {
            const _Float16 hh = (_Float16)av[j];
            ah[j] = hh;
            al[j] = (_Float16)((av[j] - (float)hh) * 2048.0f);
        }

        // 12 MFMA; dependent acc_hl pairs separated by independent MFMAs
#pragma unroll
        for (int n = 0; n < 4; ++n)
            acc_hh[n] = __builtin_amdgcn_mfma_f32_16x16x32_f16(ah, bh[n], acc_hh[n], 0, 0, 0);
#pragma unroll
        for (int n = 0; n < 4; ++n)
            acc_hl[n] = __builtin_amdgcn_mfma_f32_16x16x32_f16(ah, bl[n], acc_hl[n], 0, 0, 0);
#pragma unroll
        for (int n = 0; n < 4; ++n)
            acc_hl[n] = __builtin_amdgcn_mfma_f32_16x16x32_f16(al, bh[n], acc_hl[n], 0, 0, 0);

        __syncthreads();                 // all waves done reading chunk c
        if (c + 1 < 16) {
            *(f16x8*)&Bs[swbase]     = sr0;   // write chunk c+1
            *(f16x8*)&Bs[swbase + 8] = sr1;
            __syncthreads();
        }
    }

    // epilogue: per-wave partials -> red (aliases Bs; all B reads barriered)
#pragma unroll
    for (int n = 0; n < 4; ++n)
#pragma unroll
        for (int r = 0; r < 4; ++r)
            red[waveid * 1024 + n * 256 + r * 64 + lane] =
                acc_hh[n][r] + acc_hl[n][r] * (1.0f / 2048.0f);
    __syncthreads();

    // cross-wk reduce + coalesced write. Thread tid owns outputs o=tid*4..+3:
    // t_loc = o>>6 (0..63), e = o&63. wt_src = t_loc>>4, tl = t_loc&15.
    // Source idx (R3 mapping): (e>>4)*256 + (tl&3)*64 + (tl>>2)*16 + (e&15).
    {
        const int o      = tid * 4;
        const int t_loc  = o >> 6;
        const int e      = o & 63;
        const int wt_src = t_loc >> 4;
        const int tl     = t_loc & 15;
        const int idx    = (e >> 4) * 256 + (tl & 3) * 64 + (tl >> 2) * 16 + (e & 15);
        float4 s = *(const float4*)&red[(wt_src * 4 + 0) * 1024 + idx];
#pragma unroll
        for (int q = 1; q < 4; ++q) {
            const float4 v = *(const float4*)&red[(wt_src * 4 + q) * 1024 + idx];
            s.x += v.x; s.y += v.y; s.z += v.z; s.w += v.w;
        }
        *(float4*)(L + (size_t)(t0 + t_loc) * NEXP + e) = s;
    }
}

// ---------------------------------------------------------------------------
// Kernel 2 (cooperative): sinkhorn + top-2 + softmax gather. UNCHANGED from
// the 302us baseline. Grid = 64 blocks x 1024 threads. Wave w (0..15) of
// block b owns tokens b*256 + w*16 .. +15; lane = expert. cost in registers.
// ---------------------------------------------------------------------------
__global__ __launch_bounds__(1024) void sinkhorn_router(const float* __restrict__ L,
                                                        float* __restrict__ colbuf,
                                                        float* __restrict__ out,
                                                        int nh) {
    cooperative_groups::grid_group grid = cooperative_groups::this_grid();

    __shared__ float part[16][64];
    __shared__ float redq[64][17];
    __shared__ float d1s[64];
    __shared__ float err_s;

    const int b     = blockIdx.x;   // 0..63
    const int tid   = (int)threadIdx.x;
    const int w     = tid >> 6;     // wave 0..15
    const int lane  = tid & 63;     // expert index
    const int tbase = b * 256 + w * 16;

    float logit[16], cost[16], dreg[16];
#pragma unroll
    for (int j = 0; j < 16; ++j) {
        const int t = tbase + j;
        float l = L[(size_t)t * NEXP + lane];
        for (int h = 1; h < nh; ++h)
            l += L[(size_t)h * NTOK * NEXP + (size_t)t * NEXP + lane];
        logit[j] = l;
        cost[j]  = expf(l);
        dreg[j]  = 0.0f;
    }

    float d1l   = 1.0f;   // this lane's d1[e]
    float d1old = 1.0f;   // previous d1 (used by tid<64 for err)
    int   g     = 0;

    for (;;) {
        // ---- phase A: d0 per token + per-wave column partials ----
        float colacc = 0.0f;
#pragma unroll
        for (int j = 0; j < 16; ++j) {
            float s = d1l * cost[j];
#pragma unroll
            for (int m = 32; m; m >>= 1) s += __shfl_xor(s, m, 64);
            const float d0 = (1.0f / 16384.0f) / (s + EPSF);
            dreg[j] = d0;
            colacc = fmaf(d0, cost[j], colacc);
        }
        part[w][lane] = colacc;
        __syncthreads();

        float* cb = colbuf + (size_t)(g & 1) * (NEXP * SBLK);
        if (tid < 64) {
            float s = part[0][tid];
#pragma unroll
            for (int q = 1; q < 16; ++q) s += part[q][tid];
            cb[tid * SBLK + b] = s;     // reader-coalesced layout [e][b]
        }
        grid.sync();

        // ---- phase B: cross-block column reduction, all 1024 threads ----
        {
            const int e = tid >> 4;     // 0..63
            const int q = tid & 15;     // 0..15 -> blocks q*4..q*4+3
            const float4 v = *(const float4*)(cb + e * SBLK + q * 4);
            redq[e][q] = (v.x + v.y) + (v.z + v.w);
        }
        __syncthreads();

        if (tid < 64) {
            float tot = redq[tid][0];
#pragma unroll
            for (int q = 1; q < 16; ++q) tot += redq[tid][q];
            const float d1n = (1.0f / 64.0f) / (tot + EPSF);
            float diff = fabsf(d1old - d1n);
#pragma unroll
            for (int m = 32; m; m >>= 1) diff += __shfl_xor(diff, m, 64);
            d1s[tid] = d1n;
            d1old    = d1n;
            if (tid == 0) err_s = diff * (1.0f / 64.0f);
        }
        __syncthreads();
        d1l = d1s[lane];
        const float err = err_s;
        ++g;
        if (!(err > TOLF) || g >= 512) break;   // matches while(err>tol); NaN stops
    }

    // ---- final: per token top-2 of d1*cost*d0, softmax gather ----
#pragma unroll 1
    for (int j = 0; j < 16; ++j) {
        const int t = tbase + j;
        const float v = (d1l * cost[j]) * dreg[j];

        float bv = v; int bi = lane;
#pragma unroll
        for (int m = 32; m; m >>= 1) {
            const float ov = __shfl_xor(bv, m, 64);
            const int   oi = __shfl_xor(bi, m, 64);
            if (ov > bv || (ov == bv && oi < bi)) { bv = ov; bi = oi; }
        }
        const int i1 = bi;

        const float v2 = (lane == i1) ? -INFINITY : v;
        float bv2 = v2; int bi2 = lane;
#pragma unroll
        for (int m = 32; m; m >>= 1) {
            const float ov = __shfl_xor(bv2, m, 64);
            const int   oi = __shfl_xor(bi2, m, 64);
            if (ov > bv2 || (ov == bv2 && oi < bi2)) { bv2 = ov; bi2 = oi; }
        }
        const int i2 = bi2;

        float mx = logit[j];
#pragma unroll
        for (int m = 32; m; m >>= 1) mx = fmaxf(mx, __shfl_xor(mx, m, 64));
        const float e = expf(logit[j] - mx);
        float se = e;
#pragma unroll
        for (int m = 32; m; m >>= 1) se += __shfl_xor(se, m, 64);

        const float p1 = __shfl(e, i1, 64) / se;
        const float p2 = __shfl(e, i2, 64) / se;

        if (lane == 0) {
            out[(size_t)t * 2 + 0] = p1;
            out[(size_t)t * 2 + 1] = p2;
            out[(size_t)NTOK * 2 + (size_t)t * 2 + 0] = (float)i1;
            out[(size_t)NTOK * 2 + (size_t)t * 2 + 1] = (float)i2;
        }
    }
}

// ---------------------------------------------------------------------------
// ws layout (4.78 MB total, well under the proven-available 8.4 MB minimum):
//   [0,       256KB)  Wh f16 [64][2048]
//   [256KB,   512KB)  Wl f16 [64][2048] (pre-scaled x2048)
//   [512KB,   4.5MB)  L  f32 [16384][64]
//   [4.5MB,  +32KB )  colbuf (2 x 64 x 64 f32, sinkhorn ping-pong)
// ---------------------------------------------------------------------------
extern "C" void kernel_launch(void* const* d_in, const int* in_sizes, int n_in,
                              void* d_out, int out_size, void* d_ws, size_t ws_size,
                              hipStream_t stream) {
    const float* x = (const float*)d_in[0];
    const float* W = (const float*)d_in[1];
    float* out = (float*)d_out;

    _Float16* Wh = (_Float16*)d_ws;
    _Float16* Wl = Wh + (size_t)NEXP * HID;                  // +131072 elems
    float* L      = (float*)((char*)d_ws + 524288);
    float* colbuf = L + (size_t)NTOK * NEXP;

    convert_w<<<dim3(64), dim3(256), 0, stream>>>(W, Wh, Wl);
    gemm_mfma<<<dim3(256), dim3(1024), 0, stream>>>(x, Wh, Wl, L);

    int nh = 1;
    void* args[] = { (void*)&L, (void*)&colbuf, (void*)&out, (void*)&nh };
    hipLaunchCooperativeKernel((void*)sinkhorn_router, dim3(SBLK), dim3(1024),
                               args, 0, stream);
}

// Round 5
// 298.230 us; speedup vs baseline: 1.1262x; 1.0029x over previous
//
#include <hip/hip_runtime.h>
#include <hip/hip_cooperative_groups.h>
#include <math.h>

#define HID   2048
#define NEXP  64
#define NTOK  16384
#define SBLK  64      // sinkhorn blocks
#define TOLF  1e-4f
#define EPSF  1e-8f

typedef _Float16 f16x8 __attribute__((ext_vector_type(8)));
typedef float    f32x4 __attribute__((ext_vector_type(4)));

// ---------------------------------------------------------------------------
// Kernel 0: split W (64x2048 fp32) into Wh + Wl*2048 (f16, same [e][k] layout).
// f16x3 trick: x@W ~= xh@Wh + (xh@Wl' + xl'@Wh)/2048, residuals exact
// (Sterbenz), net error ~2^-24 * scale -- below fp32 reassociation noise.
// ---------------------------------------------------------------------------
__global__ __launch_bounds__(256) void convert_w(const float* __restrict__ W,
                                                 _Float16* __restrict__ Wh,
                                                 _Float16* __restrict__ Wl) {
    const int i = ((int)blockIdx.x * 256 + (int)threadIdx.x) * 8;
    const float4 w0 = *(const float4*)(W + i);
    const float4 w1 = *(const float4*)(W + i + 4);
    float v[8] = {w0.x, w0.y, w0.z, w0.w, w1.x, w1.y, w1.z, w1.w};
    f16x8 h, l;
#pragma unroll
    for (int j = 0; j < 8; ++j) {
        const _Float16 hh = (_Float16)v[j];
        h[j] = hh;
        l[j] = (_Float16)((v[j] - (float)hh) * 2048.0f);
    }
    *(f16x8*)(Wh + i) = h;
    *(f16x8*)(Wl + i) = l;
}

// ---------------------------------------------------------------------------
// Kernel 1: f16x3 MFMA logits, B staged through LDS. UNCHANGED from R4
// (106us -> ~69us measured; remaining cost = 2-barrier/chunk lockstep at
// 1 block/CU -- not this round's target).
// ---------------------------------------------------------------------------
#define BSTRIDE 40   // f16 per LDS B row (32 data + 8 pad, 16B-aligned)

__global__ __launch_bounds__(1024, 4) void gemm_mfma(const float* __restrict__ x,
                                                     const _Float16* __restrict__ Wh,
                                                     const _Float16* __restrict__ Wl,
                                                     float* __restrict__ L) {
    __shared__ __align__(16) char smem[65536];
    _Float16* Bs  = (_Float16*)smem;   // [(wk*2+a)*64 + row][BSTRIDE]
    float*    red = (float*)smem;      // [wave][n*256 + r*64 + lane]

    const int tid    = (int)threadIdx.x;
    const int waveid = tid >> 6;       // 0..15
    const int wt     = waveid >> 2;    // token group 0..3 (16 tokens each)
    const int wk     = waveid & 3;     // k-slice 0..3 (512 k each)
    const int lane   = tid & 63;
    const int lo     = lane & 15;      // token row (A) / expert col (D)
    const int hi     = lane >> 4;      // k-block 0..3
    const int t0     = (int)blockIdx.x * 64;
    const int kb     = wk * 512;

    const int gt    = wt * 64 + lane;  // group-local tid
    const int sa    = gt >> 7;         // 0 = Wh, 1 = Wl
    const int srow  = (gt & 127) >> 1; // 0..63
    const int shalf = (gt & 1) * 16;   // 0 or 16 (f16)
    const _Float16* sgp = (sa ? Wl : Wh) + (size_t)srow * HID + kb + shalf;
    const int swbase = ((wk * 2 + sa) * 64 + srow) * BSTRIDE + shalf;

    const float* xp = x + (size_t)(t0 + wt * 16 + lo) * HID + kb + hi * 8;

    f32x4 acc_hh[4], acc_hl[4];
#pragma unroll
    for (int n = 0; n < 4; ++n) {
        acc_hh[n] = f32x4{0.f, 0.f, 0.f, 0.f};
        acc_hl[n] = f32x4{0.f, 0.f, 0.f, 0.f};
    }

    f16x8 sr0 = *(const f16x8*)(sgp);
    f16x8 sr1 = *(const f16x8*)(sgp + 8);
    *(f16x8*)&Bs[swbase]     = sr0;
    *(f16x8*)&Bs[swbase + 8] = sr1;
    __syncthreads();

    float4 a0n = *(const float4*)(xp);
    float4 a1n = *(const float4*)(xp + 4);

    for (int c = 0; c < 16; ++c) {
        if (c + 1 < 16) {
            sr0 = *(const f16x8*)(sgp + (c + 1) * 32);
            sr1 = *(const f16x8*)(sgp + (c + 1) * 32 + 8);
        }

        const float4 a0 = a0n, a1 = a1n;
        const int ko = ((c + 1 < 16) ? (c + 1) : 15) * 32;
        a0n = *(const float4*)(xp + ko);
        a1n = *(const float4*)(xp + ko + 4);

        f16x8 bh[4], bl[4];
#pragma unroll
        for (int n = 0; n < 4; ++n) {
            bh[n] = *(const f16x8*)&Bs[((wk * 2 + 0) * 64 + lo + n * 16) * BSTRIDE + hi * 8];
            bl[n] = *(const f16x8*)&Bs[((wk * 2 + 1) * 64 + lo + n * 16) * BSTRIDE + hi * 8];
        }

        f16x8 ah, al;
        const float av[8] = {a0.x, a0.y, a0.z, a0.w, a1.x, a1.y, a1.z, a1.w};
#pragma unroll
        for (int j = 0; j < 8; ++j) {
            const _Float16 hh = (_Float16)av[j];
            ah[j] = hh;
            al[j] = (_Float16)((av[j] - (float)hh) * 2048.0f);
        }

#pragma unroll
        for (int n = 0; n < 4; ++n)
            acc_hh[n] = __builtin_amdgcn_mfma_f32_16x16x32_f16(ah, bh[n], acc_hh[n], 0, 0, 0);
#pragma unroll
        for (int n = 0; n < 4; ++n)
            acc_hl[n] = __builtin_amdgcn_mfma_f32_16x16x32_f16(ah, bl[n], acc_hl[n], 0, 0, 0);
#pragma unroll
        for (int n = 0; n < 4; ++n)
            acc_hl[n] = __builtin_amdgcn_mfma_f32_16x16x32_f16(al, bh[n], acc_hl[n], 0, 0, 0);

        __syncthreads();
        if (c + 1 < 16) {
            *(f16x8*)&Bs[swbase]     = sr0;
            *(f16x8*)&Bs[swbase + 8] = sr1;
            __syncthreads();
        }
    }

#pragma unroll
    for (int n = 0; n < 4; ++n)
#pragma unroll
        for (int r = 0; r < 4; ++r)
            red[waveid * 1024 + n * 256 + r * 64 + lane] =
                acc_hh[n][r] + acc_hl[n][r] * (1.0f / 2048.0f);
    __syncthreads();

    {
        const int o      = tid * 4;
        const int t_loc  = o >> 6;
        const int e      = o & 63;
        const int wt_src = t_loc >> 4;
        const int tl     = t_loc & 15;
        const int idx    = (e >> 4) * 256 + (tl & 3) * 64 + (tl >> 2) * 16 + (e & 15);
        float4 s = *(const float4*)&red[(wt_src * 4 + 0) * 1024 + idx];
#pragma unroll
        for (int q = 1; q < 4; ++q) {
            const float4 v = *(const float4*)&red[(wt_src * 4 + q) * 1024 + idx];
            s.x += v.x; s.y += v.y; s.z += v.z; s.w += v.w;
        }
        *(float4*)(L + (size_t)(t0 + t_loc) * NEXP + e) = s;
    }
}

// ---------------------------------------------------------------------------
// wave-wide f32 sum via DPP (VALU-only; replaces 6 ds_swizzle ops). rocPRIM/
// LLVM canonical: row_shr 1/2/4/8 accumulates within 16-lane rows (bound_ctrl
// =true: invalid src lanes read 0), row_bcast15 (rows 1,3) and row_bcast31
// (rows 2,3) merge rows; lane 63 holds the total. readlane -> wave-uniform.
// R4 post-mortem: phase A's 96 DS ops/wave/iter on the shared per-CU LDS
// unit (~9.2K cyc/CU/iter) was the dominant sinkhorn cost.
// ---------------------------------------------------------------------------
__device__ __forceinline__ float wave_sum64(float v) {
    int x;
    float t;
    x = __builtin_bit_cast(int, v);
    t = __builtin_bit_cast(float, __builtin_amdgcn_update_dpp(0, x, 0x111, 0xf, 0xf, true)); v += t;
    x = __builtin_bit_cast(int, v);
    t = __builtin_bit_cast(float, __builtin_amdgcn_update_dpp(0, x, 0x112, 0xf, 0xf, true)); v += t;
    x = __builtin_bit_cast(int, v);
    t = __builtin_bit_cast(float, __builtin_amdgcn_update_dpp(0, x, 0x114, 0xf, 0xf, true)); v += t;
    x = __builtin_bit_cast(int, v);
    t = __builtin_bit_cast(float, __builtin_amdgcn_update_dpp(0, x, 0x118, 0xf, 0xf, true)); v += t;
    x = __builtin_bit_cast(int, v);
    t = __builtin_bit_cast(float, __builtin_amdgcn_update_dpp(0, x, 0x142, 0xa, 0xf, true)); v += t;
    x = __builtin_bit_cast(int, v);
    t = __builtin_bit_cast(float, __builtin_amdgcn_update_dpp(0, x, 0x143, 0xc, 0xf, true)); v += t;
    return __builtin_bit_cast(float, __builtin_amdgcn_readlane(__builtin_bit_cast(int, v), 63));
}

// ---------------------------------------------------------------------------
// Kernel 2 (cooperative): sinkhorn + top-2 + softmax gather.
// R5 change: phase A row-sum via wave_sum64 (DPP) instead of shfl_xor
// butterfly; d0 becomes wave-uniform scalar. Everything else unchanged.
// Grid = 64 blocks x 1024 threads. Wave w owns tokens b*256+w*16..+15;
// lane = expert. cost in registers.
// ---------------------------------------------------------------------------
__global__ __launch_bounds__(1024) void sinkhorn_router(const float* __restrict__ L,
                                                        float* __restrict__ colbuf,
                                                        float* __restrict__ out,
                                                        int nh) {
    cooperative_groups::grid_group grid = cooperative_groups::this_grid();

    __shared__ float part[16][64];
    __shared__ float redq[64][17];
    __shared__ float d1s[64];
    __shared__ float err_s;

    const int b     = blockIdx.x;   // 0..63
    const int tid   = (int)threadIdx.x;
    const int w     = tid >> 6;     // wave 0..15
    const int lane  = tid & 63;     // expert index
    const int tbase = b * 256 + w * 16;

    float logit[16], cost[16], dreg[16];
#pragma unroll
    for (int j = 0; j < 16; ++j) {
        const int t = tbase + j;
        float l = L[(size_t)t * NEXP + lane];
        for (int h = 1; h < nh; ++h)
            l += L[(size_t)h * NTOK * NEXP + (size_t)t * NEXP + lane];
        logit[j] = l;
        cost[j]  = expf(l);
        dreg[j]  = 0.0f;
    }

    float d1l   = 1.0f;   // this lane's d1[e]
    float d1old = 1.0f;   // previous d1 (used by tid<64 for err)
    int   g     = 0;

    for (;;) {
        // ---- phase A: d0 per token (DPP reduce) + per-wave column partials
        float colacc = 0.0f;
#pragma unroll
        for (int j = 0; j < 16; ++j) {
            const float s = wave_sum64(d1l * cost[j]);   // wave-uniform
            const float d0 = (1.0f / 16384.0f) / (s + EPSF);
            dreg[j] = d0;
            colacc = fmaf(d0, cost[j], colacc);
        }
        part[w][lane] = colacc;
        __syncthreads();

        float* cb = colbuf + (size_t)(g & 1) * (NEXP * SBLK);
        if (tid < 64) {
            float s = part[0][tid];
#pragma unroll
            for (int q = 1; q < 16; ++q) s += part[q][tid];
            cb[tid * SBLK + b] = s;     // reader-coalesced layout [e][b]
        }
        grid.sync();

        // ---- phase B: cross-block column reduction, all 1024 threads ----
        {
            const int e = tid >> 4;     // 0..63
            const int q = tid & 15;     // 0..15 -> blocks q*4..q*4+3
            const float4 v = *(const float4*)(cb + e * SBLK + q * 4);
            redq[e][q] = (v.x + v.y) + (v.z + v.w);
        }
        __syncthreads();

        if (tid < 64) {
            float tot = redq[tid][0];
#pragma unroll
            for (int q = 1; q < 16; ++q) tot += redq[tid][q];
            const float d1n = (1.0f / 64.0f) / (tot + EPSF);
            float diff = fabsf(d1old - d1n);
#pragma unroll
            for (int m = 32; m; m >>= 1) diff += __shfl_xor(diff, m, 64);
            d1s[tid] = d1n;
            d1old    = d1n;
            if (tid == 0) err_s = diff * (1.0f / 64.0f);
        }
        __syncthreads();
        d1l = d1s[lane];
        const float err = err_s;
        ++g;
        if (!(err > TOLF) || g >= 512) break;   // matches while(err>tol); NaN stops
    }

    // ---- final: per token top-2 of d1*cost*d0, softmax gather ----
#pragma unroll 1
    for (int j = 0; j < 16; ++j) {
        const int t = tbase + j;
        const float v = (d1l * cost[j]) * dreg[j];

        float bv = v; int bi = lane;
#pragma unroll
        for (int m = 32; m; m >>= 1) {
            const float ov = __shfl_xor(bv, m, 64);
            const int   oi = __shfl_xor(bi, m, 64);
            if (ov > bv || (ov == bv && oi < bi)) { bv = ov; bi = oi; }
        }
        const int i1 = bi;

        const float v2 = (lane == i1) ? -INFINITY : v;
        float bv2 = v2; int bi2 = lane;
#pragma unroll
        for (int m = 32; m; m >>= 1) {
            const float ov = __shfl_xor(bv2, m, 64);
            const int   oi = __shfl_xor(bi2, m, 64);
            if (ov > bv2 || (ov == bv2 && oi < bi2)) { bv2 = ov; bi2 = oi; }
        }
        const int i2 = bi2;

        float mx = logit[j];
#pragma unroll
        for (int m = 32; m; m >>= 1) mx = fmaxf(mx, __shfl_xor(mx, m, 64));
        const float e = expf(logit[j] - mx);
        float se = e;
#pragma unroll
        for (int m = 32; m; m >>= 1) se += __shfl_xor(se, m, 64);

        const float p1 = __shfl(e, i1, 64) / se;
        const float p2 = __shfl(e, i2, 64) / se;

        if (lane == 0) {
            out[(size_t)t * 2 + 0] = p1;
            out[(size_t)t * 2 + 1] = p2;
            out[(size_t)NTOK * 2 + (size_t)t * 2 + 0] = (float)i1;
            out[(size_t)NTOK * 2 + (size_t)t * 2 + 1] = (float)i2;
        }
    }
}

// ---------------------------------------------------------------------------
// ws layout (4.78 MB total, well under the proven-available 8.4 MB minimum):
//   [0,       256KB)  Wh f16 [64][2048]
//   [256KB,   512KB)  Wl f16 [64][2048] (pre-scaled x2048)
//   [512KB,   4.5MB)  L  f32 [16384][64]
//   [4.5MB,  +32KB )  colbuf (2 x 64 x 64 f32, sinkhorn ping-pong)
// ---------------------------------------------------------------------------
extern "C" void kernel_launch(void* const* d_in, const int* in_sizes, int n_in,
                              void* d_out, int out_size, void* d_ws, size_t ws_size,
                              hipStream_t stream) {
    const float* x = (const float*)d_in[0];
    const float* W = (const float*)d_in[1];
    float* out = (float*)d_out;

    _Float16* Wh = (_Float16*)d_ws;
    _Float16* Wl = Wh + (size_t)NEXP * HID;                  // +131072 elems
    float* L      = (float*)((char*)d_ws + 524288);
    float* colbuf = L + (size_t)NTOK * NEXP;

    convert_w<<<dim3(64), dim3(256), 0, stream>>>(W, Wh, Wl);
    gemm_mfma<<<dim3(256), dim3(1024), 0, stream>>>(x, Wh, Wl, L);

    int nh = 1;
    void* args[] = { (void*)&L, (void*)&colbuf, (void*)&out, (void*)&nh };
    hipLaunchCooperativeKernel((void*)sinkhorn_router, dim3(SBLK), dim3(1024),
                               args, 0, stream);
}